// Round 6
// baseline (218.076 us; speedup 1.0000x reference)
//
#include <hip/hip_runtime.h>
#include <math.h>

// Problem constants
#define V    4
#define T    4
#define NSRC 100000   // NS
#define NHX  12288    // NH
#define E    100000
#define H    64
#define VT   16       // (v,t') edge types

#define SL   8             // dst-sort slices per vt
#define SLE  (E/SL)        // 12500 edges per slice
#define RCH  2             // src ranges for deg_out hist
#define RBINS (NSRC/RCH)   // 50000 u8 bins
#define RW   (RBINS/4)     // 12500 packed words = 50 KB LDS
#define NPB  8             // nodes per epilogue block

// ---------------------------------------------------------------------------
// K0: transpose x[v][t][s] -> x4[v][s] = {t=0..3}, nan_to_num folded in.
// ---------------------------------------------------------------------------
__global__ void transpose_kernel(const float* __restrict__ x,
                                 float4* __restrict__ x4) {
    const int v = blockIdx.y;
    const int s = blockIdx.x * 256 + threadIdx.x;
    if (s >= NSRC) return;
    const float* xr = x + (size_t)v * T * NSRC + s;
    float a0 = xr[0], a1 = xr[NSRC], a2 = xr[2 * NSRC], a3 = xr[3 * NSRC];
    float4 r;
    r.x = (a0 == a0) ? a0 : 0.0f;
    r.y = (a1 == a1) ? a1 : 0.0f;
    r.z = (a2 == a2) ? a2 : 0.0f;
    r.w = (a3 == a3) ? a3 : 0.0f;
    x4[(size_t)v * NSRC + s] = r;
}

// ---------------------------------------------------------------------------
// K1: ns[vt][s] = rsqrt(max(deg_out,1)). u8 quads in u32 LDS words; block
// (rg,vt) owns src range [rg*50000,..) and scans ALL E edges of vt, so each
// bin is complete in one block -> write ns directly, no partials.
// Max per-src degree ~12 << 255 -> no u8 overflow.
// ---------------------------------------------------------------------------
__global__ void __launch_bounds__(1024)
ns_kernel(const int* __restrict__ src, float* __restrict__ ns) {
    const int rg = blockIdx.x, vt = blockIdx.y;
    const int lo = rg * RBINS;
    __shared__ unsigned int pack[RW];           // 50 KB
    for (int i = threadIdx.x; i < RW; i += 1024) pack[i] = 0u;
    __syncthreads();
    const int* s_row = src + vt * E;
    for (int e = threadIdx.x; e < E; e += 1024) {
        const unsigned r = (unsigned)(s_row[e] - lo);
        if (r < RBINS) atomicAdd(&pack[r >> 2], 1u << ((r & 3) * 8));
    }
    __syncthreads();
    float4* nsp = (float4*)(ns + (size_t)vt * NSRC + lo);
    for (int w = threadIdx.x; w < RW; w += 1024) {
        const unsigned u = pack[w];
        float4 r4;
        r4.x = rsqrtf(fmaxf((float)(u & 0xFFu), 1.0f));
        r4.y = rsqrtf(fmaxf((float)((u >> 8) & 0xFFu), 1.0f));
        r4.z = rsqrtf(fmaxf((float)((u >> 16) & 0xFFu), 1.0f));
        r4.w = rsqrtf(fmaxf((float)(u >> 24), 1.0f));
        nsp[w] = r4;
    }
}

// ---------------------------------------------------------------------------
// K2: per-(vt,slice) dst histograms (full NHX fits in 48 KB LDS, no filter).
// ---------------------------------------------------------------------------
__global__ void __launch_bounds__(1024)
dhist_kernel(const int* __restrict__ dst, unsigned int* __restrict__ ph) {
    const int sl = blockIdx.x, vt = blockIdx.y;
    __shared__ unsigned int h[NHX];             // 48 KB
    for (int i = threadIdx.x; i < NHX; i += 1024) h[i] = 0u;
    __syncthreads();
    const int* d_row = dst + vt * E + sl * SLE;
    for (int e = threadIdx.x; e < SLE; e += 1024)
        atomicAdd(&h[d_row[e]], 1u);
    __syncthreads();
    unsigned int* outp = ph + ((size_t)vt * SL + sl) * NHX;
    for (int i = threadIdx.x; i < NHX; i += 1024) outp[i] = h[i];
}

// ---------------------------------------------------------------------------
// K3: per-vt CSR scan. start[vt][sl][d] = colstart of d + slice prefix;
// also colstart, degs, and ndst = rsqrt(max(deg_in,1)).
// Block-wide exclusive scan: wave shfl scan + serial 16-wave combine.
// ---------------------------------------------------------------------------
__global__ void __launch_bounds__(1024)
dscan_kernel(const unsigned int* __restrict__ ph,
             unsigned int* __restrict__ start,
             unsigned int* __restrict__ colstart,
             unsigned int* __restrict__ degs,
             float* __restrict__ ndst) {
    const int vt   = blockIdx.x;
    const int tid  = threadIdx.x;
    const int lane = tid & 63, wv = tid >> 6;
    __shared__ unsigned int wsum[16];
    __shared__ unsigned int running;
    if (tid == 0) running = 0u;
    __syncthreads();
    for (int ch = 0; ch < NHX / 1024; ++ch) {
        const int d = ch * 1024 + tid;
        unsigned int h[SL];
        unsigned int tot = 0;
#pragma unroll
        for (int s = 0; s < SL; ++s) {
            h[s] = ph[((size_t)vt * SL + s) * NHX + d];
            tot += h[s];
        }
        unsigned int incl = tot;
#pragma unroll
        for (int off = 1; off < 64; off <<= 1) {
            const unsigned int vup = (unsigned int)__shfl_up((int)incl, off, 64);
            if (lane >= off) incl += vup;
        }
        if (lane == 63) wsum[wv] = incl;
        __syncthreads();
        if (tid == 0) {
            unsigned int r = running;
#pragma unroll
            for (int w = 0; w < 16; ++w) { const unsigned int t2 = wsum[w]; wsum[w] = r; r += t2; }
            running = r;
        }
        __syncthreads();
        const unsigned int base = wsum[wv] + (incl - tot);
        colstart[(size_t)vt * NHX + d] = base;
        degs[(size_t)vt * NHX + d]     = tot;
        ndst[(size_t)vt * NHX + d]     = rsqrtf(fmaxf((float)tot, 1.0f));
        unsigned int acc = base;
#pragma unroll
        for (int s = 0; s < SL; ++s) {
            start[((size_t)vt * SL + s) * NHX + d] = acc;
            acc += h[s];
        }
        __syncthreads();   // wsum reuse guard
    }
}

// ---------------------------------------------------------------------------
// K4: reorder. Block (sl,vt) loads its slice's start offsets into LDS,
// assigns positions via LDS atomics, scatters src ids into sorted order.
// ---------------------------------------------------------------------------
__global__ void __launch_bounds__(1024)
reorder_kernel(const int* __restrict__ src, const int* __restrict__ dst,
               const unsigned int* __restrict__ start,
               int* __restrict__ sorted) {
    const int sl = blockIdx.x, vt = blockIdx.y;
    __shared__ unsigned int pos[NHX];           // 48 KB
    const unsigned int* st = start + ((size_t)vt * SL + sl) * NHX;
    for (int i = threadIdx.x; i < NHX; i += 1024) pos[i] = st[i];
    __syncthreads();
    const int* s_row = src + vt * E + sl * SLE;
    const int* d_row = dst + vt * E + sl * SLE;
    int* outp = sorted + (size_t)vt * E;
    for (int e = threadIdx.x; e < SLE; e += 1024) {
        const int d = d_row[e];
        const int s = s_row[e];
        const unsigned int p = atomicAdd(&pos[d], 1u);
        outp[p] = s;
    }
}

// ---------------------------------------------------------------------------
// K5: atomic-free accumulation. One thread per (vt,d): contiguous sorted
// segment, x4/ns gathers (L2-resident via XCD-vt swizzle), float4 sval write.
// ---------------------------------------------------------------------------
__global__ void __launch_bounds__(256)
accum_kernel(const float4* __restrict__ x4, const int* __restrict__ sorted,
             const float* __restrict__ ns,
             const unsigned int* __restrict__ colstart,
             const unsigned int* __restrict__ degs,
             const float* __restrict__ ndst,
             float4* __restrict__ sval) {
    const int b = blockIdx.x;            // 768 = 8 XCD * 2 vt * 48 chunks
    const int k = b & 7;
    const int j = b >> 3;
    const int vt = 2 * k + (j & 1);
    const int chunk = j >> 1;            // 0..47
    const int d = chunk * 256 + threadIdx.x;
    const int v = vt >> 2;
    const size_t vd = (size_t)vt * NHX + d;
    const unsigned int base = colstart[vd];
    const unsigned int deg  = degs[vd];
    const float nd = ndst[vd];
    const int*    srt    = sorted + (size_t)vt * E;
    const float*  ns_row = ns + (size_t)vt * NSRC;
    const float4* x_row  = x4 + (size_t)v * NSRC;
    float4 acc = make_float4(0.f, 0.f, 0.f, 0.f);
    for (unsigned int i = 0; i < deg; ++i) {
        const int s = srt[base + i];
        const float4 xv = x_row[s];
        const float  nv = ns_row[s];
        acc.x += xv.x * nv; acc.y += xv.y * nv;
        acc.z += xv.z * nv; acc.w += xv.w * nv;
    }
    acc.x *= nd; acc.y *= nd; acc.z *= nd; acc.w *= nd;
    sval[vd] = acc;
}

// ---------------------------------------------------------------------------
// K6: epilogue. Block handles NPB=8 nodes; math identical to verified R5.
// ---------------------------------------------------------------------------
__global__ void epilogue_kernel(const float4* __restrict__ sval,
                                const float* __restrict__ Wm,
                                const float* __restrict__ bm,
                                float* __restrict__ out) {
    const int n0  = blockIdx.x * NPB;
    const int tid = threadIdx.x;
    __shared__ float sW[VT * H];
    __shared__ float sb[VT * H];
    __shared__ float sv[VT][T][NPB];

    for (int i = tid; i < VT * H; i += 256) { sW[i] = Wm[i]; sb[i] = bm[i]; }
    if (tid < VT * NPB) {                 // 128 threads load 128 float4s
        const int vt = tid >> 3, n = tid & 7;
        const float4 r = sval[(size_t)vt * NHX + n0 + n];
        sv[vt][0][n] = r.x; sv[vt][1][n] = r.y;
        sv[vt][2][n] = r.z; sv[vt][3][n] = r.w;
    }
    __syncthreads();

    const int v  = tid >> 6;
    const int t  = (tid >> 4) & 3;
    const int hb = (tid & 15) * 4;
    float4 Wr[4], Br[4];
#pragma unroll
    for (int tp = 0; tp < 4; ++tp) {
        const int wi = (v * 4 + tp) * H + hb;
        Wr[tp] = *(const float4*)&sW[wi];
        Br[tp] = *(const float4*)&sb[wi];
    }
#pragma unroll
    for (int n = 0; n < NPB; ++n) {
        float4 o = make_float4(0.f, 0.f, 0.f, 0.f);
#pragma unroll
        for (int tp = 0; tp < 4; ++tp) {
            const float s = sv[v * 4 + tp][t][n];
            float a;
            a = fmaf(s, Wr[tp].x, Br[tp].x); o.x += (a > 0.f) ? a : 0.01f * a;
            a = fmaf(s, Wr[tp].y, Br[tp].y); o.y += (a > 0.f) ? a : 0.01f * a;
            a = fmaf(s, Wr[tp].z, Br[tp].z); o.z += (a > 0.f) ? a : 0.01f * a;
            a = fmaf(s, Wr[tp].w, Br[tp].w); o.w += (a > 0.f) ? a : 0.01f * a;
        }
        ((float4*)(out + (size_t)(n0 + n) * (V * T * H)))[tid] = o;
    }
}

// ---------------------------------------------------------------------------
extern "C" void kernel_launch(void* const* d_in, const int* in_sizes, int n_in,
                              void* d_out, int out_size, void* d_ws, size_t ws_size,
                              hipStream_t stream) {
    const float* x   = (const float*)d_in[0];   // [V,T,NS]
    const float* Wm  = (const float*)d_in[1];   // [V,T,H]
    const float* bm  = (const float*)d_in[2];   // [V,T,H]
    const int*   src = (const int*)d_in[3];     // [V,T,E]
    const int*   dst = (const int*)d_in[4];     // [V,T,E]
    float* out = (float*)d_out;                 // [NH,V,T,H]

    // workspace ~37.3 MB; every region fully written before read, no memset.
    // All region sizes are multiples of 16 B -> float4 alignment holds.
    char* ws = (char*)d_ws;
    size_t off = 0;
    float4* x4 = (float4*)(ws + off);            off += (size_t)V * NSRC * sizeof(float4);   // 6.4 MB
    float4* sval = (float4*)(ws + off);          off += (size_t)VT * NHX * sizeof(float4);   // 3.1 MB
    float* ns = (float*)(ws + off);              off += (size_t)VT * NSRC * sizeof(float);   // 6.4 MB
    unsigned int* ph = (unsigned int*)(ws + off);       off += (size_t)VT * SL * NHX * 4;    // 6.3 MB
    unsigned int* start = (unsigned int*)(ws + off);    off += (size_t)VT * SL * NHX * 4;    // 6.3 MB
    unsigned int* colstart = (unsigned int*)(ws + off); off += (size_t)VT * NHX * 4;         // 0.8 MB
    unsigned int* degs = (unsigned int*)(ws + off);     off += (size_t)VT * NHX * 4;         // 0.8 MB
    float* ndst = (float*)(ws + off);                   off += (size_t)VT * NHX * 4;         // 0.8 MB
    int* sorted = (int*)(ws + off);                     off += (size_t)VT * E * 4;           // 6.4 MB

    transpose_kernel<<<dim3((NSRC + 255) / 256, V), 256, 0, stream>>>(x, x4);
    ns_kernel<<<dim3(RCH, VT), 1024, 0, stream>>>(src, ns);
    dhist_kernel<<<dim3(SL, VT), 1024, 0, stream>>>(dst, ph);
    dscan_kernel<<<VT, 1024, 0, stream>>>(ph, start, colstart, degs, ndst);
    reorder_kernel<<<dim3(SL, VT), 1024, 0, stream>>>(src, dst, start, sorted);
    accum_kernel<<<768, 256, 0, stream>>>(x4, sorted, ns, colstart, degs, ndst, sval);
    epilogue_kernel<<<NHX / NPB, 256, 0, stream>>>(sval, Wm, bm, out);
}

// Round 7
// 148.717 us; speedup vs baseline: 1.4664x; 1.4664x over previous
//
#include <hip/hip_runtime.h>
#include <math.h>

// Problem constants
#define V    4
#define T    4
#define NSRC 100000   // NS
#define NHX  12288    // NH
#define E    100000
#define H    64
#define VT   16       // (v,t') edge types

#define SL    8            // dst-sort slices per vt
#define SLE   (E/SL)       // 12500 edges per slice
#define RCH   2            // src ranges for deg_out hist (u8 packed)
#define RBINS (NSRC/RCH)   // 50000 u8 bins -> 12500 words (50 KB LDS)
#define RW    (RBINS/4)
#define HF    8            // edge slices for deg_out hist
#define HE    (E/HF)       // 12500
#define NW    (NSRC/4)     // 25000 packed words per vt in cnt_part
#define NCH   12           // 1024-wide d-chunks per vt (NHX = 12*1024)
#define NPB   8            // nodes per epilogue block

// S1 sub-grid offsets
#define S1_TRANS  391                      // ceil(V*NSRC/1024)
#define S1_CNT    (RCH*HF*VT)              // 256
#define S1_DHIST  (SL*VT)                  // 128
// S2 sub-grid
#define S2_SCAN   (NCH*VT)                 // 192
#define S2_NSFIN  391                      // ceil(VT*NW/1024)

// ---------------------------------------------------------------------------
// S1: fused input-only stage.
//  blocks [0,391): transpose x[v][t][s] -> x4[v][s] (nan_to_num folded)
//  blocks [391,647): deg_out partial hist, u8 quads in u32 LDS words
//  blocks [647,775): per-(vt,slice) dst histograms + chunk-total atomics
// ---------------------------------------------------------------------------
__global__ void __launch_bounds__(1024)
s1_kernel(const float* __restrict__ x, const int* __restrict__ src,
          const int* __restrict__ dst, float4* __restrict__ x4,
          unsigned int* __restrict__ cnt_part, unsigned int* __restrict__ ph,
          unsigned int* __restrict__ blocksum) {
    __shared__ unsigned int lds[RW];               // 50 KB (union for both branches)
    const int b = blockIdx.x, tid = threadIdx.x;

    if (b < S1_TRANS) {                            // ---- transpose ----
        const int g = b * 1024 + tid;
        if (g < V * NSRC) {
            const int v = g / NSRC, s = g - v * NSRC;
            const float* xr = x + (size_t)v * T * NSRC + s;
            float a0 = xr[0], a1 = xr[NSRC], a2 = xr[2 * NSRC], a3 = xr[3 * NSRC];
            float4 r;
            r.x = (a0 == a0) ? a0 : 0.0f;
            r.y = (a1 == a1) ? a1 : 0.0f;
            r.z = (a2 == a2) ? a2 : 0.0f;
            r.w = (a3 == a3) ? a3 : 0.0f;
            x4[g] = r;
        }
        return;
    }
    if (b < S1_TRANS + S1_CNT) {                   // ---- deg_out hist ----
        const int idx = b - S1_TRANS;
        const int rg = idx & 1;
        const int hf = (idx >> 1) & 7;
        const int vt = idx >> 4;
        const int lo = rg * RBINS;
        for (int i = tid; i < RW; i += 1024) lds[i] = 0u;
        __syncthreads();
        const int* s_row = src + vt * E + hf * HE;
        for (int e = tid; e < HE; e += 1024) {
            const unsigned r = (unsigned)(s_row[e] - lo);
            if (r < RBINS) atomicAdd(&lds[r >> 2], 1u << ((r & 3) * 8));
        }
        __syncthreads();
        unsigned int* outp = cnt_part + ((size_t)hf * VT + vt) * NW + rg * RW;
        for (int i = tid; i < RW; i += 1024) outp[i] = lds[i];
        return;
    }
    {                                              // ---- dst hist ----
        const int idx = b - (S1_TRANS + S1_CNT);
        const int sl = idx & 7, vt = idx >> 3;
        for (int i = tid; i < NHX; i += 1024) lds[i] = 0u;
        __syncthreads();
        const int* d_row = dst + vt * E + sl * SLE;
        for (int e = tid; e < SLE; e += 1024)
            atomicAdd(&lds[d_row[e]], 1u);
        __syncthreads();
        unsigned int* outp = ph + ((size_t)vt * SL + sl) * NHX;
        for (int i = tid; i < NHX; i += 1024) outp[i] = lds[i];
        // publish per-chunk totals (wave w handles chunk w)
        const int lane = tid & 63, wv = tid >> 6;
        if (wv < NCH) {
            unsigned int s = 0;
#pragma unroll
            for (int i = 0; i < 16; ++i) s += lds[wv * 1024 + i * 64 + lane];
#pragma unroll
            for (int off = 32; off > 0; off >>= 1)
                s += (unsigned int)__shfl_down((int)s, off, 64);
            if (lane == 0) atomicAdd(&blocksum[vt * NCH + wv], s);
        }
    }
}

// ---------------------------------------------------------------------------
// S2: fused nsfin + CSR scan.
//  blocks [0,192): chunk (ch,vt) scan -> colstart/degs/start (self-base from
//                  blocksum; wave shfl scan + 16-wave combine)
//  blocks [192,583): ns[vt][s] = rsqrt(max(deg_out,1)) from u8 partials
// ---------------------------------------------------------------------------
__global__ void __launch_bounds__(1024)
s2_kernel(const unsigned int* __restrict__ cnt_part,
          const unsigned int* __restrict__ ph,
          const unsigned int* __restrict__ blocksum,
          float4* __restrict__ ns4,
          unsigned int* __restrict__ start,
          unsigned int* __restrict__ colstart,
          unsigned int* __restrict__ degs) {
    const int b = blockIdx.x, tid = threadIdx.x;

    if (b < S2_SCAN) {                             // ---- scan ----
        const int vt = b & 15, ch = b >> 4;
        const int lane = tid & 63, wv = tid >> 6;
        const int d = ch * 1024 + tid;
        __shared__ unsigned int wsum[16];
        __shared__ unsigned int sbase;
        if (tid == 0) {
            unsigned int base = 0;
            for (int c = 0; c < ch; ++c) base += blocksum[vt * NCH + c];
            sbase = base;
        }
        unsigned int h[SL];
        unsigned int tot = 0;
#pragma unroll
        for (int s = 0; s < SL; ++s) {
            h[s] = ph[((size_t)vt * SL + s) * NHX + d];
            tot += h[s];
        }
        unsigned int incl = tot;
#pragma unroll
        for (int off = 1; off < 64; off <<= 1) {
            const unsigned int vup = (unsigned int)__shfl_up((int)incl, off, 64);
            if (lane >= off) incl += vup;
        }
        if (lane == 63) wsum[wv] = incl;
        __syncthreads();
        if (tid == 0) {
            unsigned int run = sbase;
#pragma unroll
            for (int w = 0; w < 16; ++w) { const unsigned int t2 = wsum[w]; wsum[w] = run; run += t2; }
        }
        __syncthreads();
        const unsigned int excl = wsum[wv] + (incl - tot);
        const size_t vd = (size_t)vt * NHX + d;
        colstart[vd] = excl;
        degs[vd]     = tot;
        unsigned int acc = excl;
#pragma unroll
        for (int s = 0; s < SL; ++s) {
            start[((size_t)vt * SL + s) * NHX + d] = acc;
            acc += h[s];
        }
        return;
    }
    {                                              // ---- nsfin ----
        const int g = (b - S2_SCAN) * 1024 + tid;  // word index into VT*NW
        if (g >= VT * NW) return;
        const int vt = g / NW;
        unsigned c0 = 0, c1 = 0, c2 = 0, c3 = 0;
#pragma unroll
        for (int hf = 0; hf < HF; ++hf) {
            const unsigned w = cnt_part[(size_t)hf * VT * NW + g
                                        - (size_t)vt * NW + (size_t)vt * NW];
            c0 += w & 0xFFu; c1 += (w >> 8) & 0xFFu;
            c2 += (w >> 16) & 0xFFu; c3 += w >> 24;
        }
        float4 r;
        r.x = rsqrtf(fmaxf((float)c0, 1.0f));
        r.y = rsqrtf(fmaxf((float)c1, 1.0f));
        r.z = rsqrtf(fmaxf((float)c2, 1.0f));
        r.w = rsqrtf(fmaxf((float)c3, 1.0f));
        ns4[g] = r;
    }
}

// ---------------------------------------------------------------------------
// S3: reorder (counting-sort placement). XCD swizzle: XCD k owns vt={2k,2k+1}
// so scattered 4B stores stay within 800 KB of L2-resident sorted rows.
// ---------------------------------------------------------------------------
__global__ void __launch_bounds__(1024)
s3_reorder(const int* __restrict__ src, const int* __restrict__ dst,
           const unsigned int* __restrict__ start, int* __restrict__ sorted) {
    const int b = blockIdx.x;              // 128 = 8 XCD * 2 vt * 8 sl
    const int k = b & 7, j = b >> 3;
    const int vt = 2 * k + (j & 1);
    const int sl = j >> 1;
    __shared__ unsigned int pos[NHX];      // 48 KB
    const unsigned int* st = start + ((size_t)vt * SL + sl) * NHX;
    for (int i = threadIdx.x; i < NHX; i += 1024) pos[i] = st[i];
    __syncthreads();
    const int* s_row = src + vt * E + sl * SLE;
    const int* d_row = dst + vt * E + sl * SLE;
    int* outp = sorted + (size_t)vt * E;
    for (int e = threadIdx.x; e < SLE; e += 1024) {
        const int d = d_row[e];
        const int s = s_row[e];
        const unsigned int p = atomicAdd(&pos[d], 1u);
        outp[p] = s;
    }
}

// ---------------------------------------------------------------------------
// S4: atomic-free accumulation. One thread per (vt,d); contiguous sorted
// segment; 2-wide gather ILP; XCD swizzle keeps x4/ns/sorted rows in L2.
// ---------------------------------------------------------------------------
__global__ void __launch_bounds__(256)
s4_accum(const float4* __restrict__ x4, const int* __restrict__ sorted,
         const float* __restrict__ ns,
         const unsigned int* __restrict__ colstart,
         const unsigned int* __restrict__ degs,
         float4* __restrict__ sval) {
    const int b = blockIdx.x;              // 768 = 8 XCD * 2 vt * 48 chunks
    const int k = b & 7, j = b >> 3;
    const int vt = 2 * k + (j & 1);
    const int chunk = j >> 1;
    const int d = chunk * 256 + threadIdx.x;
    const int v = vt >> 2;
    const size_t vd = (size_t)vt * NHX + d;
    const unsigned int base = colstart[vd];
    const unsigned int deg  = degs[vd];
    const float nd = rsqrtf(fmaxf((float)deg, 1.0f));
    const int*    srt    = sorted + (size_t)vt * E;
    const float*  ns_row = ns + (size_t)vt * NSRC;
    const float4* x_row  = x4 + (size_t)v * NSRC;
    float4 acc = make_float4(0.f, 0.f, 0.f, 0.f);
    unsigned int i = 0;
    for (; i + 2 <= deg; i += 2) {
        const int s0 = srt[base + i];
        const int s1 = srt[base + i + 1];
        const float4 xa = x_row[s0]; const float na = ns_row[s0];
        const float4 xb = x_row[s1]; const float nb = ns_row[s1];
        acc.x += xa.x * na + xb.x * nb;
        acc.y += xa.y * na + xb.y * nb;
        acc.z += xa.z * na + xb.z * nb;
        acc.w += xa.w * na + xb.w * nb;
    }
    if (i < deg) {
        const int s0 = srt[base + i];
        const float4 xa = x_row[s0]; const float na = ns_row[s0];
        acc.x += xa.x * na; acc.y += xa.y * na;
        acc.z += xa.z * na; acc.w += xa.w * na;
    }
    acc.x *= nd; acc.y *= nd; acc.z *= nd; acc.w *= nd;
    sval[vd] = acc;
}

// ---------------------------------------------------------------------------
// S5: epilogue (verified math). Block handles NPB=8 nodes.
// ---------------------------------------------------------------------------
__global__ void __launch_bounds__(256)
s5_epilogue(const float4* __restrict__ sval, const float* __restrict__ Wm,
            const float* __restrict__ bm, float* __restrict__ out) {
    const int n0  = blockIdx.x * NPB;
    const int tid = threadIdx.x;
    __shared__ float sW[VT * H];
    __shared__ float sb[VT * H];
    __shared__ float sv[VT][T][NPB];

    for (int i = tid; i < VT * H; i += 256) { sW[i] = Wm[i]; sb[i] = bm[i]; }
    if (tid < VT * NPB) {
        const int vt = tid >> 3, n = tid & 7;
        const float4 r = sval[(size_t)vt * NHX + n0 + n];
        sv[vt][0][n] = r.x; sv[vt][1][n] = r.y;
        sv[vt][2][n] = r.z; sv[vt][3][n] = r.w;
    }
    __syncthreads();

    const int v  = tid >> 6;
    const int t  = (tid >> 4) & 3;
    const int hb = (tid & 15) * 4;
    float4 Wr[4], Br[4];
#pragma unroll
    for (int tp = 0; tp < 4; ++tp) {
        const int wi = (v * 4 + tp) * H + hb;
        Wr[tp] = *(const float4*)&sW[wi];
        Br[tp] = *(const float4*)&sb[wi];
    }
#pragma unroll
    for (int n = 0; n < NPB; ++n) {
        float4 o = make_float4(0.f, 0.f, 0.f, 0.f);
#pragma unroll
        for (int tp = 0; tp < 4; ++tp) {
            const float s = sv[v * 4 + tp][t][n];
            float a;
            a = fmaf(s, Wr[tp].x, Br[tp].x); o.x += (a > 0.f) ? a : 0.01f * a;
            a = fmaf(s, Wr[tp].y, Br[tp].y); o.y += (a > 0.f) ? a : 0.01f * a;
            a = fmaf(s, Wr[tp].z, Br[tp].z); o.z += (a > 0.f) ? a : 0.01f * a;
            a = fmaf(s, Wr[tp].w, Br[tp].w); o.w += (a > 0.f) ? a : 0.01f * a;
        }
        ((float4*)(out + (size_t)(n0 + n) * (V * T * H)))[tid] = o;
    }
}

// ---------------------------------------------------------------------------
extern "C" void kernel_launch(void* const* d_in, const int* in_sizes, int n_in,
                              void* d_out, int out_size, void* d_ws, size_t ws_size,
                              hipStream_t stream) {
    const float* x   = (const float*)d_in[0];   // [V,T,NS]
    const float* Wm  = (const float*)d_in[1];   // [V,T,H]
    const float* bm  = (const float*)d_in[2];   // [V,T,H]
    const int*   src = (const int*)d_in[3];     // [V,T,E]
    const int*   dst = (const int*)d_in[4];     // [V,T,E]
    float* out = (float*)d_out;                 // [NH,V,T,H]

    // workspace ~49.3 MB; blocksum memset-init, all else fully written
    // before read. All region sizes multiples of 16 B.
    char* ws = (char*)d_ws;
    size_t off = 0;
    float4* x4 = (float4*)(ws + off);                   off += (size_t)V * NSRC * 16;      // 6.40 MB
    float4* sval = (float4*)(ws + off);                 off += (size_t)VT * NHX * 16;      // 3.15 MB
    float4* ns4 = (float4*)(ws + off);                  off += (size_t)VT * NSRC * 4;      // 6.40 MB
    unsigned int* ph = (unsigned int*)(ws + off);       off += (size_t)VT * SL * NHX * 4;  // 6.29 MB
    unsigned int* start = (unsigned int*)(ws + off);    off += (size_t)VT * SL * NHX * 4;  // 6.29 MB
    unsigned int* colstart = (unsigned int*)(ws + off); off += (size_t)VT * NHX * 4;       // 0.79 MB
    unsigned int* degs = (unsigned int*)(ws + off);     off += (size_t)VT * NHX * 4;       // 0.79 MB
    unsigned int* blocksum = (unsigned int*)(ws + off); off += 1024;                       // 192 u32 + pad
    unsigned int* cnt_part = (unsigned int*)(ws + off); off += (size_t)HF * VT * NW * 4;   // 12.80 MB
    int* sorted = (int*)(ws + off);                     off += (size_t)VT * E * 4;         // 6.40 MB
    float* ns = (float*)ns4;

    hipMemsetAsync(blocksum, 0, VT * NCH * sizeof(unsigned int), stream);
    s1_kernel<<<S1_TRANS + S1_CNT + S1_DHIST, 1024, 0, stream>>>(
        x, src, dst, x4, cnt_part, ph, blocksum);
    s2_kernel<<<S2_SCAN + S2_NSFIN, 1024, 0, stream>>>(
        cnt_part, ph, blocksum, ns4, start, colstart, degs);
    s3_reorder<<<SL * VT, 1024, 0, stream>>>(src, dst, start, sorted);
    s4_accum<<<768, 256, 0, stream>>>(x4, sorted, ns, colstart, degs, sval);
    s5_epilogue<<<NHX / NPB, 256, 0, stream>>>(sval, Wm, bm, out);
}

// Round 8
// 145.343 us; speedup vs baseline: 1.5004x; 1.0232x over previous
//
#include <hip/hip_runtime.h>
#include <math.h>

// Problem constants
#define V    4
#define T    4
#define NSRC 100000   // NS
#define NHX  12288    // NH
#define E    100000
#define H    64
#define VT   16       // (v,t') edge types

#define SL    16           // dst-sort slices per vt
#define SLE   (E/SL)       // 6250 edges per slice
#define RCH   2            // src ranges for deg_out hist (u8 packed)
#define RBINS (NSRC/RCH)   // 50000 u8 bins -> 12500 words (50 KB LDS)
#define RW    (RBINS/4)
#define HF    8            // edge slices for deg_out hist
#define HE    (E/HF)       // 12500
#define NW    (NSRC/4)     // 25000 packed words per vt in cnt_part
#define NCH   12           // 1024-wide d-chunks per vt (NHX = 12*1024)
#define NPB   8            // nodes per epilogue block

// S1 sub-grid offsets
#define S1_TRANS  391                      // ceil(V*NSRC/1024)
#define S1_CNT    (RCH*HF*VT)              // 256
#define S1_DHIST  (SL*VT)                  // 256
// S2 sub-grid
#define S2_SCAN   (NCH*VT)                 // 192
#define S2_NSFIN  391                      // ceil(VT*NW/1024)

typedef float vf4 __attribute__((ext_vector_type(4)));

// ---------------------------------------------------------------------------
// S1: fused input-only stage.
//  [0,391): transpose x[v][t][s] -> x4[v][s] (nan_to_num folded)
//  [391,647): deg_out partial hist, u8 quads in u32 LDS words
//  [647,903): per-(vt,slice) dst histograms + non-atomic chunk sums cs
// ---------------------------------------------------------------------------
__global__ void __launch_bounds__(1024)
s1_kernel(const float* __restrict__ x, const int* __restrict__ src,
          const int* __restrict__ dst, float4* __restrict__ x4,
          unsigned int* __restrict__ cnt_part, unsigned int* __restrict__ ph,
          unsigned int* __restrict__ cs) {
    __shared__ unsigned int lds[RW];               // 50 KB (union for both branches)
    const int b = blockIdx.x, tid = threadIdx.x;

    if (b < S1_TRANS) {                            // ---- transpose ----
        const int g = b * 1024 + tid;
        if (g < V * NSRC) {
            const int v = g / NSRC, s = g - v * NSRC;
            const float* xr = x + (size_t)v * T * NSRC + s;
            float a0 = xr[0], a1 = xr[NSRC], a2 = xr[2 * NSRC], a3 = xr[3 * NSRC];
            float4 r;
            r.x = (a0 == a0) ? a0 : 0.0f;
            r.y = (a1 == a1) ? a1 : 0.0f;
            r.z = (a2 == a2) ? a2 : 0.0f;
            r.w = (a3 == a3) ? a3 : 0.0f;
            x4[g] = r;
        }
        return;
    }
    if (b < S1_TRANS + S1_CNT) {                   // ---- deg_out hist ----
        const int idx = b - S1_TRANS;
        const int rg = idx & 1;
        const int hf = (idx >> 1) & 7;
        const int vt = idx >> 4;
        const int lo = rg * RBINS;
        for (int i = tid; i < RW; i += 1024) lds[i] = 0u;
        __syncthreads();
        const int* s_row = src + vt * E + hf * HE;
        for (int e = tid; e < HE; e += 1024) {
            const unsigned r = (unsigned)(s_row[e] - lo);
            if (r < RBINS) atomicAdd(&lds[r >> 2], 1u << ((r & 3) * 8));
        }
        __syncthreads();
        unsigned int* outp = cnt_part + ((size_t)hf * VT + vt) * NW + rg * RW;
        for (int i = tid; i < RW; i += 1024) outp[i] = lds[i];
        return;
    }
    {                                              // ---- dst hist ----
        const int idx = b - (S1_TRANS + S1_CNT);
        const int sl = idx & 15, vt = idx >> 4;
        for (int i = tid; i < NHX; i += 1024) lds[i] = 0u;
        __syncthreads();
        const int* d_row = dst + vt * E + sl * SLE;
        for (int e = tid; e < SLE; e += 1024)
            atomicAdd(&lds[d_row[e]], 1u);
        __syncthreads();
        unsigned int* outp = ph + ((size_t)vt * SL + sl) * NHX;
        for (int i = tid; i < NHX; i += 1024) outp[i] = lds[i];
        // non-atomic per-chunk totals: wave wv sums chunk wv
        const int lane = tid & 63, wv = tid >> 6;
        if (wv < NCH) {
            unsigned int s = 0;
#pragma unroll
            for (int i = 0; i < 16; ++i) s += lds[wv * 1024 + i * 64 + lane];
#pragma unroll
            for (int off = 32; off > 0; off >>= 1)
                s += (unsigned int)__shfl_down((int)s, off, 64);
            if (lane == 0) cs[((size_t)vt * SL + sl) * NCH + wv] = s;
        }
    }
}

// ---------------------------------------------------------------------------
// S2: fused CSR scan + nsfin.
//  [0,192): chunk (ch,vt) scan -> colstart/degs/start (base from cs sums)
//  [192,583): ns[vt][s] = rsqrt(max(deg_out,1)) from u8 partials
// ---------------------------------------------------------------------------
__global__ void __launch_bounds__(1024)
s2_kernel(const unsigned int* __restrict__ cnt_part,
          const unsigned int* __restrict__ ph,
          const unsigned int* __restrict__ cs,
          float4* __restrict__ ns4,
          unsigned int* __restrict__ start,
          unsigned int* __restrict__ colstart,
          unsigned int* __restrict__ degs) {
    const int b = blockIdx.x, tid = threadIdx.x;

    if (b < S2_SCAN) {                             // ---- scan ----
        const int vt = b & 15, ch = b >> 4;
        const int lane = tid & 63, wv = tid >> 6;
        const int d = ch * 1024 + tid;
        __shared__ unsigned int wsum[16];
        __shared__ unsigned int sbase;
        // parallel chunk base: lane l (<16) sums slice l over chunks < ch
        if (wv == 0) {
            unsigned int p = 0;
            if (lane < SL)
                for (int c = 0; c < ch; ++c)
                    p += cs[((size_t)vt * SL + lane) * NCH + c];
#pragma unroll
            for (int off = 8; off > 0; off >>= 1)
                p += (unsigned int)__shfl_down((int)p, off, 64);
            if (lane == 0) sbase = p;
        }
        unsigned int h[SL];
        unsigned int tot = 0;
#pragma unroll
        for (int s = 0; s < SL; ++s) {
            h[s] = ph[((size_t)vt * SL + s) * NHX + d];
            tot += h[s];
        }
        unsigned int incl = tot;
#pragma unroll
        for (int off = 1; off < 64; off <<= 1) {
            const unsigned int vup = (unsigned int)__shfl_up((int)incl, off, 64);
            if (lane >= off) incl += vup;
        }
        if (lane == 63) wsum[wv] = incl;
        __syncthreads();
        if (tid == 0) {
            unsigned int run = sbase;
#pragma unroll
            for (int w = 0; w < 16; ++w) { const unsigned int t2 = wsum[w]; wsum[w] = run; run += t2; }
        }
        __syncthreads();
        const unsigned int excl = wsum[wv] + (incl - tot);
        const size_t vd = (size_t)vt * NHX + d;
        colstart[vd] = excl;
        degs[vd]     = tot;
        unsigned int acc = excl;
#pragma unroll
        for (int s = 0; s < SL; ++s) {
            start[((size_t)vt * SL + s) * NHX + d] = acc;
            acc += h[s];
        }
        return;
    }
    {                                              // ---- nsfin ----
        const int g = (b - S2_SCAN) * 1024 + tid;  // word index (vt*NW+w)
        if (g >= VT * NW) return;
        unsigned c0 = 0, c1 = 0, c2 = 0, c3 = 0;
#pragma unroll
        for (int hf = 0; hf < HF; ++hf) {
            const unsigned w = cnt_part[(size_t)hf * VT * NW + g];
            c0 += w & 0xFFu; c1 += (w >> 8) & 0xFFu;
            c2 += (w >> 16) & 0xFFu; c3 += w >> 24;
        }
        float4 r;
        r.x = rsqrtf(fmaxf((float)c0, 1.0f));
        r.y = rsqrtf(fmaxf((float)c1, 1.0f));
        r.z = rsqrtf(fmaxf((float)c2, 1.0f));
        r.w = rsqrtf(fmaxf((float)c3, 1.0f));
        ns4[g] = r;
    }
}

// ---------------------------------------------------------------------------
// S3: reorder (counting-sort placement). 256 blocks, XCD swizzle: XCD k owns
// vt={2k,2k+1} so scattered stores stay in the L2-resident sorted rows.
// ---------------------------------------------------------------------------
__global__ void __launch_bounds__(1024)
s3_reorder(const int* __restrict__ src, const int* __restrict__ dst,
           const unsigned int* __restrict__ start, int* __restrict__ sorted) {
    const int b = blockIdx.x;              // 256 = 8 XCD * 2 vt * 16 sl
    const int k = b & 7, j = b >> 3;
    const int vt = 2 * k + (j & 1);
    const int sl = j >> 1;
    __shared__ unsigned int pos[NHX];      // 48 KB
    const unsigned int* st = start + ((size_t)vt * SL + sl) * NHX;
    for (int i = threadIdx.x; i < NHX; i += 1024) pos[i] = st[i];
    __syncthreads();
    const int* s_row = src + vt * E + sl * SLE;
    const int* d_row = dst + vt * E + sl * SLE;
    int* outp = sorted + (size_t)vt * E;
    for (int e = threadIdx.x; e < SLE; e += 1024) {
        const int d = d_row[e];
        const int s = s_row[e];
        const unsigned int p = atomicAdd(&pos[d], 1u);
        outp[p] = s;
    }
}

// ---------------------------------------------------------------------------
// S4: atomic-free accumulation. TWO threads per (vt,d): interleaved segment
// halves, combined via shfl_xor -> wave tail latency halves. XCD swizzle.
// ---------------------------------------------------------------------------
__global__ void __launch_bounds__(256)
s4_accum(const float4* __restrict__ x4, const int* __restrict__ sorted,
         const float* __restrict__ ns,
         const unsigned int* __restrict__ colstart,
         const unsigned int* __restrict__ degs,
         float4* __restrict__ sval) {
    const int b = blockIdx.x;              // 1536 = 8 XCD * 2 vt * 96 chunks
    const int k = b & 7, j = b >> 3;       // j 0..191
    const int vt = 2 * k + (j & 1);
    const int chunk = j >> 1;              // 0..95
    const int d = chunk * 128 + (threadIdx.x >> 1);
    const int half = threadIdx.x & 1;
    const int v = vt >> 2;
    const size_t vd = (size_t)vt * NHX + d;
    const unsigned int base = colstart[vd];
    const unsigned int deg  = degs[vd];
    const int*    srt    = sorted + (size_t)vt * E;
    const float*  ns_row = ns + (size_t)vt * NSRC;
    const float4* x_row  = x4 + (size_t)v * NSRC;
    float4 acc = make_float4(0.f, 0.f, 0.f, 0.f);
    for (unsigned int i = half; i < deg; i += 2) {
        const int s = srt[base + i];
        const float4 xa = x_row[s];
        const float  na = ns_row[s];
        acc.x += xa.x * na; acc.y += xa.y * na;
        acc.z += xa.z * na; acc.w += xa.w * na;
    }
    acc.x += __shfl_xor(acc.x, 1, 64);
    acc.y += __shfl_xor(acc.y, 1, 64);
    acc.z += __shfl_xor(acc.z, 1, 64);
    acc.w += __shfl_xor(acc.w, 1, 64);
    if (half == 0) {
        const float nd = rsqrtf(fmaxf((float)deg, 1.0f));
        acc.x *= nd; acc.y *= nd; acc.z *= nd; acc.w *= nd;
        sval[vd] = acc;
    }
}

// ---------------------------------------------------------------------------
// S5: epilogue (verified math). Block handles NPB=8 nodes; nontemporal out.
// ---------------------------------------------------------------------------
__global__ void __launch_bounds__(256)
s5_epilogue(const float4* __restrict__ sval, const float* __restrict__ Wm,
            const float* __restrict__ bm, float* __restrict__ out) {
    const int n0  = blockIdx.x * NPB;
    const int tid = threadIdx.x;
    __shared__ float sW[VT * H];
    __shared__ float sb[VT * H];
    __shared__ float sv[VT][T][NPB];

    for (int i = tid; i < VT * H; i += 256) { sW[i] = Wm[i]; sb[i] = bm[i]; }
    if (tid < VT * NPB) {
        const int vt = tid >> 3, n = tid & 7;
        const float4 r = sval[(size_t)vt * NHX + n0 + n];
        sv[vt][0][n] = r.x; sv[vt][1][n] = r.y;
        sv[vt][2][n] = r.z; sv[vt][3][n] = r.w;
    }
    __syncthreads();

    const int v  = tid >> 6;
    const int t  = (tid >> 4) & 3;
    const int hb = (tid & 15) * 4;
    float4 Wr[4], Br[4];
#pragma unroll
    for (int tp = 0; tp < 4; ++tp) {
        const int wi = (v * 4 + tp) * H + hb;
        Wr[tp] = *(const float4*)&sW[wi];
        Br[tp] = *(const float4*)&sb[wi];
    }
#pragma unroll
    for (int n = 0; n < NPB; ++n) {
        float4 o = make_float4(0.f, 0.f, 0.f, 0.f);
#pragma unroll
        for (int tp = 0; tp < 4; ++tp) {
            const float s = sv[v * 4 + tp][t][n];
            float a;
            a = fmaf(s, Wr[tp].x, Br[tp].x); o.x += (a > 0.f) ? a : 0.01f * a;
            a = fmaf(s, Wr[tp].y, Br[tp].y); o.y += (a > 0.f) ? a : 0.01f * a;
            a = fmaf(s, Wr[tp].z, Br[tp].z); o.z += (a > 0.f) ? a : 0.01f * a;
            a = fmaf(s, Wr[tp].w, Br[tp].w); o.w += (a > 0.f) ? a : 0.01f * a;
        }
        vf4* dstp = (vf4*)(out + (size_t)(n0 + n) * (V * T * H)) + tid;
        __builtin_nontemporal_store(*(vf4*)&o, dstp);
    }
}

// ---------------------------------------------------------------------------
extern "C" void kernel_launch(void* const* d_in, const int* in_sizes, int n_in,
                              void* d_out, int out_size, void* d_ws, size_t ws_size,
                              hipStream_t stream) {
    const float* x   = (const float*)d_in[0];   // [V,T,NS]
    const float* Wm  = (const float*)d_in[1];   // [V,T,H]
    const float* bm  = (const float*)d_in[2];   // [V,T,H]
    const int*   src = (const int*)d_in[3];     // [V,T,E]
    const int*   dst = (const int*)d_in[4];     // [V,T,E]
    float* out = (float*)d_out;                 // [NH,V,T,H]

    // workspace ~62 MB; every region fully written before read -> no memset.
    // All region sizes multiples of 16 B.
    char* ws = (char*)d_ws;
    size_t off = 0;
    float4* x4 = (float4*)(ws + off);                   off += (size_t)V * NSRC * 16;        // 6.40 MB
    float4* sval = (float4*)(ws + off);                 off += (size_t)VT * NHX * 16;        // 3.15 MB
    float4* ns4 = (float4*)(ws + off);                  off += (size_t)VT * NSRC * 4;        // 6.40 MB
    unsigned int* ph = (unsigned int*)(ws + off);       off += (size_t)VT * SL * NHX * 4;    // 12.58 MB
    unsigned int* start = (unsigned int*)(ws + off);    off += (size_t)VT * SL * NHX * 4;    // 12.58 MB
    unsigned int* colstart = (unsigned int*)(ws + off); off += (size_t)VT * NHX * 4;         // 0.79 MB
    unsigned int* degs = (unsigned int*)(ws + off);     off += (size_t)VT * NHX * 4;         // 0.79 MB
    unsigned int* cs = (unsigned int*)(ws + off);       off += (size_t)VT * SL * NCH * 4;    // 12 KB
    unsigned int* cnt_part = (unsigned int*)(ws + off); off += (size_t)HF * VT * NW * 4;     // 12.80 MB
    int* sorted = (int*)(ws + off);                     off += (size_t)VT * E * 4;           // 6.40 MB
    float* ns = (float*)ns4;

    s1_kernel<<<S1_TRANS + S1_CNT + S1_DHIST, 1024, 0, stream>>>(
        x, src, dst, x4, cnt_part, ph, cs);
    s2_kernel<<<S2_SCAN + S2_NSFIN, 1024, 0, stream>>>(
        cnt_part, ph, cs, ns4, start, colstart, degs);
    s3_reorder<<<SL * VT, 1024, 0, stream>>>(src, dst, start, sorted);
    s4_accum<<<1536, 256, 0, stream>>>(x4, sorted, ns, colstart, degs, sval);
    s5_epilogue<<<NHX / NPB, 256, 0, stream>>>(sval, Wm, bm, out);
}